// Round 9
// baseline (137.546 us; speedup 1.0000x reference)
//
#include <hip/hip_runtime.h>
#include <hip/hip_bf16.h>

// Problem constants
#define M_TOK 4928   // B*T = 64*77
#define M_PAD 5120   // 40*128 and 20*256
#define D_DIM 768
#define NR    4096   // N*R = 1024*4
#define K_CAT 4864   // NR + D_DIM (concat-K for gemm2)
#define KT_ALL 152   // K_CAT / 32 (BK32 units)
#define NT64_ALL 76  // K_CAT / 64 (BK64 units)

typedef __bf16 bf16;
typedef __attribute__((ext_vector_type(8))) __bf16 bf16x8;
typedef __attribute__((ext_vector_type(4))) float f32x4;
typedef __attribute__((address_space(1))) uint32_t gu32;
typedef __attribute__((address_space(3))) uint32_t su32;

// tanh-form gelu via sigmoid; max abs err ~3e-4 (budget: 1.6e-2 vs 5.8e-2 thr)
__device__ __forceinline__ float gelu_fast(float v) {
  float p = v * v;
  float u = v * fmaf(0.07135481283f, p, 1.595769122f);
  float e = __expf(-u);
  return v * __builtin_amdgcn_rcpf(1.0f + e);
}

// m204 bijective XCD swizzle: consecutive logical wgids land on one XCD.
__device__ __forceinline__ int xcd_swizzle(int orig, int nwg) {
  const int q = nwg >> 3, r = nwg & 7;
  const int x = orig & 7, rest = orig >> 3;
  return (x < r ? x * (q + 1) : r * (q + 1) + (x - r) * q) + rest;
}

// ---------------- prep kernels ----------------

__global__ __launch_bounds__(256) void k_prep_x(const float* __restrict__ x,
                                                bf16* __restrict__ Xb) {
  int idx = (blockIdx.x * 256 + threadIdx.x) * 4;
  if (idx >= M_PAD * D_DIM) return;
  int m = idx / D_DIM;
  union { uint2 u; bf16 h[4]; } o;
  if (m < M_TOK) {
    float4 v = *(const float4*)(x + idx);
    o.h[0] = (bf16)v.x; o.h[1] = (bf16)v.y; o.h[2] = (bf16)v.z; o.h[3] = (bf16)v.w;
  } else {
    o.h[0] = o.h[1] = o.h[2] = o.h[3] = (bf16)0.0f;
  }
  *(uint2*)(Xb + idx) = o.u;
}

// w1 fp32 [N=1024][D=768][R=4] -> W1t bf16 [4096 j][768 d] (K-major), j = n*4+r
__global__ __launch_bounds__(256) void k_prep_w1t(const float* __restrict__ w1,
                                                  bf16* __restrict__ W1t) {
  int idx = (blockIdx.x * 256 + threadIdx.x) * 4;
  if (idx >= NR * D_DIM) return;
  int j = idx / D_DIM, d0 = idx % D_DIM;
  int n = j >> 2, r = j & 3;
  const float* src = w1 + n * (D_DIM * 4) + r;
  union { uint2 u; bf16 h[4]; } o;
#pragma unroll
  for (int i = 0; i < 4; ++i) o.h[i] = (bf16)src[(d0 + i) * 4];
  *(uint2*)(W1t + idx) = o.u;
}

// w_out fp32 [4096 k][768 d] -> W2t[d][k] (x0.25) via LDS 64x64 transpose.
__global__ __launch_bounds__(256) void k_prep_w2t_t(const float* __restrict__ w_out,
                                                    bf16* __restrict__ W2t) {
  __shared__ float S[64 * 65];
  const int bk = blockIdx.x & 63, bd = blockIdx.x >> 6;  // 64 k-tiles x 12 d-tiles
  const int k0 = bk * 64, d0 = bd * 64;
  const int tr = threadIdx.x >> 4;        // 0..15
  const int tc = (threadIdx.x & 15) * 4;  // 0..60
#pragma unroll
  for (int p = 0; p < 4; ++p) {
    const int kr = tr + p * 16;
    float4 v = *(const float4*)(w_out + (size_t)(k0 + kr) * D_DIM + d0 + tc);
    S[kr * 65 + tc + 0] = v.x; S[kr * 65 + tc + 1] = v.y;
    S[kr * 65 + tc + 2] = v.z; S[kr * 65 + tc + 3] = v.w;
  }
  __syncthreads();
#pragma unroll
  for (int p = 0; p < 4; ++p) {
    const int dr = tr + p * 16;
    union { uint2 u; bf16 h[4]; } o;
#pragma unroll
    for (int i = 0; i < 4; ++i) o.h[i] = (bf16)(0.25f * S[(tc + i) * 65 + dr]);
    *(uint2*)(W2t + (size_t)(d0 + dr) * K_CAT + k0 + tc) = o.u;
  }
}

// W_org fp32 [768 d][768 k] -> W2t[d][4096 + k]  (row-major: plain copy)
__global__ __launch_bounds__(256) void k_prep_w2t_org(const float* __restrict__ W_org,
                                                      bf16* __restrict__ W2t) {
  int idx = (blockIdx.x * 256 + threadIdx.x) * 4;
  if (idx >= D_DIM * D_DIM) return;
  int d = idx / D_DIM, c = idx % D_DIM;
  float4 v = *(const float4*)(W_org + idx);
  union { uint2 u; bf16 h[4]; } o;
  o.h[0] = (bf16)v.x; o.h[1] = (bf16)v.y; o.h[2] = (bf16)v.z; o.h[3] = (bf16)v.w;
  *(uint2*)(W2t + (size_t)d * K_CAT + NR + c) = o.u;
}

// bias_total[d] = b_org[d] + 0.25 * sum_n b_out[n][d]  (deterministic 2-stage)
__global__ __launch_bounds__(256) void k_bias_partial(const float* __restrict__ b_out,
                                                      float* __restrict__ partial) {
  int b = blockIdx.x;
  for (int d = threadIdx.x; d < D_DIM; d += 256) {
    float s = 0.0f;
    for (int n = b * 32; n < b * 32 + 32; ++n) s += b_out[n * D_DIM + d];
    partial[b * D_DIM + d] = s;
  }
}

__global__ __launch_bounds__(256) void k_bias_final(const float* __restrict__ partial,
                                                    const float* __restrict__ b_org,
                                                    float* __restrict__ bias_total) {
  int d = blockIdx.x * 256 + threadIdx.x;
  if (d >= D_DIM) return;
  float s = 0.0f;
#pragma unroll
  for (int b = 0; b < 32; ++b) s += partial[b * D_DIM + d];
  bias_total[d] = b_org[d] + 0.25f * s;
}

// ---------------- GEMM1 (R8 structure, unchanged) ----------------
// Bank-conflict swizzle (R4-verified: conflicts -> 0): 16B slot p of row r
// holds logical slot p ^ ((r>>1)&3); source pre-swizzled, ds_read XORs back.

__device__ __forceinline__ int swz_slot(int kg, int lr) {
  return (kg ^ ((lr >> 1) & 3)) << 3;  // bf16 elements
}

// 4-wave (256-thread) stage of a 128x32 bf16 tile: 2 insts/wave.
__device__ __forceinline__ void stage_tile4(const bf16* g, int ld, int row0, int col0,
                                            bf16* lds) {
  const int lane = threadIdx.x & 63;
  const int wave = threadIdx.x >> 6;  // 0..3
  const int src_slot = (lane & 3) ^ ((lane >> 3) & 3);
#pragma unroll
  for (int c = 0; c < 2; ++c) {
    const int chunk = wave * 2 + c;   // 0..7
    const int row = row0 + chunk * 16 + (lane >> 2);
    const bf16* gp = g + (size_t)row * ld + col0 + (src_slot << 3);
    __builtin_amdgcn_global_load_lds((gu32*)gp, (su32*)(lds + chunk * 512), 16, 0, 0);
  }
}

#define TILE_E (128 * 32)

// 3-buffer counted-vmcnt pipeline: tiles t,t+1 in flight, vmcnt(4) per iter.
#define PIPE_LOOP(KT0, KT1, STAGE_PAIR, BODY)                                   \
  {                                                                             \
    STAGE_PAIR(KT0, 0);                                                         \
    STAGE_PAIR((KT0) + 1, 1);                                                   \
    int ra = 0;                                                                 \
    for (int kt = (KT0); kt < (KT1); ++kt) {                                    \
      if (kt + 1 < (KT1)) { asm volatile("s_waitcnt vmcnt(4)" ::: "memory"); }  \
      else                { asm volatile("s_waitcnt vmcnt(0)" ::: "memory"); }  \
      asm volatile("s_barrier" ::: "memory");                                   \
      const int rs = ra + 2 >= 3 ? ra - 1 : ra + 2;                             \
      BODY(ra);                                                                 \
      if (kt + 2 < (KT1)) STAGE_PAIR(kt + 2, rs);                               \
      ra = (ra + 1 == 3) ? 0 : ra + 1;                                          \
    }                                                                           \
  }

// GEMM1: Xb[5120,768] x W1t[4096,768] -> H2 bf16 [5120,4096]
__global__ __launch_bounds__(256) void k_gemm1(const bf16* __restrict__ Xb,
                                               const bf16* __restrict__ W1t,
                                               bf16* __restrict__ H2,
                                               const float* __restrict__ b1,
                                               const float* __restrict__ midw,
                                               const float* __restrict__ midb) {
  __shared__ bf16 As[3][TILE_E];
  __shared__ bf16 Bs[3][TILE_E];
  const int wgid = xcd_swizzle(blockIdx.x, 40 * 32);
  const int bmt = wgid >> 5;             // 40 M-tiles of 128
  const int bnt = wgid & 31;             // 32 N-tiles (consecutive share A-panel)
  const int m0 = bmt * 128, n0 = bnt * 128;
  const int lane = threadIdx.x & 63;
  const int wave = threadIdx.x >> 6;
  const int wm = wave >> 1, wn = wave & 1;
  const int lr = lane & 15, kg = lane >> 4;
  const int slot = swz_slot(kg, lr);

  f32x4 acc[4][4];
#pragma unroll
  for (int i = 0; i < 4; ++i)
#pragma unroll
    for (int j = 0; j < 4; ++j) acc[i][j] = (f32x4)(0.0f);

#define G1_STAGE(kt, buf)                                   \
  {                                                         \
    stage_tile4(Xb, D_DIM, m0, (kt) * 32, As[(buf)]);       \
    stage_tile4(W1t, D_DIM, n0, (kt) * 32, Bs[(buf)]);      \
  }
#define G1_BODY(cur)                                                         \
  {                                                                          \
    bf16x8 a[4], b[4];                                                       \
    _Pragma("unroll") for (int i = 0; i < 4; ++i)                            \
      a[i] = *(const bf16x8*)(As[(cur)] + (wm * 64 + i * 16 + lr) * 32 + slot); \
    _Pragma("unroll") for (int j = 0; j < 4; ++j)                            \
      b[j] = *(const bf16x8*)(Bs[(cur)] + (wn * 64 + j * 16 + lr) * 32 + slot); \
    _Pragma("unroll") for (int i = 0; i < 4; ++i)                            \
      _Pragma("unroll") for (int j = 0; j < 4; ++j)                          \
        acc[i][j] = __builtin_amdgcn_mfma_f32_16x16x32_bf16(a[i], b[j], acc[i][j], 0, 0, 0); \
  }

  PIPE_LOOP(0, 24, G1_STAGE, G1_BODY)
#undef G1_STAGE
#undef G1_BODY

#pragma unroll
  for (int j = 0; j < 4; ++j) {
    const int col = n0 + wn * 64 + j * 16 + lr;
    const float b1v = b1[col];
    const float mdv = midw[(col >> 2) * 16 + (col & 3) * 5];  // mid_w[n][r][r]
    const float mbv = midb[col];
#pragma unroll
    for (int i = 0; i < 4; ++i) {
      const int r0 = m0 + wm * 64 + i * 16 + kg * 4;
#pragma unroll
      for (int rr = 0; rr < 4; ++rr) {
        float h = acc[i][j][rr] + b1v;
        h = gelu_fast(h);
        h = h * mdv + mbv;
        h = gelu_fast(h);
        H2[(size_t)(r0 + rr) * NR + col] = (bf16)h;
      }
    }
  }
}

// ---------------- GEMM2: 256x256, BK=64, 4-phase engine ----------------
// LDS layout per tile: [256 rows][64 cols] bf16, rows = 8 slots of 16B.
// Swizzle: physical slot q of row r holds logical slot q ^ (r&7) (involution);
// source pre-swizzled (rule 21), ds_read XORs back. Residual 2-way = free.

// stage one 256x64 bf16 tile (32 KB): 32 chunks of 8 rows; 4 insts/wave (8 waves).
__device__ __forceinline__ void stage64(const bf16* g, int ld, int row0, int col0,
                                        bf16* lds) {
  const int lane = threadIdx.x & 63;
  const int wave = threadIdx.x >> 6;       // 0..7
  const int rsub = lane >> 3;              // row within chunk 0..7
  const int src_slot = (lane & 7) ^ rsub;  // pre-swizzled global 16B-slot
#pragma unroll
  for (int c = 0; c < 4; ++c) {
    const int chunk = wave * 4 + c;        // 0..31
    const int row = row0 + chunk * 8 + rsub;
    const bf16* gp = g + (size_t)row * ld + col0 + (src_slot << 3);
    __builtin_amdgcn_global_load_lds((gu32*)gp, (su32*)(lds + chunk * 512), 16, 0, 0);
  }
}

// GEMM2: A = [H2 | Xb] (K=4864) x W2t[768,4864] -> bf16 partials / fp32 out.
// Per K-tile (BK=64): top {vmcnt(8) + barrier}; then 4 phases
// {ds_read -> barrier -> setprio(1) 16 MFMA setprio(0) -> barrier}; stage(t+2)
// placed in P4 after lgkmcnt(0)+barrier (slot-s reads globally retired).
template <int SPLITS>
__global__ __launch_bounds__(512) void k_gemm2(const bf16* __restrict__ H2,
                                               const bf16* __restrict__ Xb,
                                               const bf16* __restrict__ W2t,
                                               void* __restrict__ outp,
                                               const float* __restrict__ bias) {
  __shared__ bf16 As[2][256 * 64];
  __shared__ bf16 Bs[2][256 * 64];
  const int nwg = 20 * 3 * SPLITS;
  const int wgid = xcd_swizzle(blockIdx.x, nwg);
  const int bmt = wgid / (3 * SPLITS);
  const int rem = wgid % (3 * SPLITS);
  const int ks  = rem / 3;
  const int bnt = rem % 3;               // 3 consecutive share A-panel
  const int m0 = bmt * 256, n0 = bnt * 256;
  const int lane = threadIdx.x & 63;
  const int wave = threadIdx.x >> 6;
  const int wm = wave >> 2, wn = wave & 3;
  const int lr = lane & 15, kg = lane >> 4;
  // ds_read element offsets: row lr within 16-row group, slot (kg ^ (lr&7))
  // for k-slice 0; k-slice 1 flips slot bit2 -> element-index ^ 32.
  const int c0  = lr * 64 + ((kg ^ (lr & 7)) << 3);
  const int aB0 = wm * 8192 + c0;        // + i*1024 ; ^32 for k-slice 1
  const int bB0 = wn * 4096 + c0;        // + j*1024
  constexpr int NT = NT64_ALL / SPLITS;  // 19 / 38 / 76
  const int t0 = ks * NT;

  f32x4 acc[8][4];
#pragma unroll
  for (int i = 0; i < 8; ++i)
#pragma unroll
    for (int j = 0; j < 4; ++j) acc[i][j] = (f32x4)(0.0f);

#define G2_SA(t, s)                                                     \
  {                                                                     \
    const int k0s = (t0 + (t)) * 64;                                    \
    if (k0s < NR) stage64(H2, NR, m0, k0s, As[(s)]);                    \
    else          stage64(Xb, D_DIM, m0, k0s - NR, As[(s)]);            \
  }
#define G2_SB(t, s) stage64(W2t, K_CAT, n0, (t0 + (t)) * 64, Bs[(s)])

  G2_SA(0, 0); G2_SB(0, 0);
  G2_SA(1, 1); G2_SB(1, 1);

  for (int t = 0; t < NT; ++t) {
    const int s = t & 1;
    const bf16* Ap = As[s];
    const bf16* Bp = Bs[s];
    // tile t landed (per-wave FIFO: <=8 outstanding => older retired) + global
    if (t + 1 < NT) { asm volatile("s_waitcnt vmcnt(8)" ::: "memory"); }
    else            { asm volatile("s_waitcnt vmcnt(0)" ::: "memory"); }
    asm volatile("s_barrier" ::: "memory");

    bf16x8 a[4], b[4];
    // ---- P1: i0-3, k-slice 0 ----
#pragma unroll
    for (int i = 0; i < 4; ++i) a[i] = *(const bf16x8*)(Ap + aB0 + i * 1024);
#pragma unroll
    for (int j = 0; j < 4; ++j) b[j] = *(const bf16x8*)(Bp + bB0 + j * 1024);
    asm volatile("s_barrier" ::: "memory");
    __builtin_amdgcn_s_setprio(1);
#pragma unroll
    for (int i = 0; i < 4; ++i)
#pragma unroll
      for (int j = 0; j < 4; ++j)
        acc[i][j] = __builtin_amdgcn_mfma_f32_16x16x32_bf16(a[i], b[j], acc[i][j], 0, 0, 0);
    __builtin_amdgcn_s_setprio(0);
    asm volatile("s_barrier" ::: "memory");
    // ---- P2: i4-7, k-slice 0 ----
#pragma unroll
    for (int i = 0; i < 4; ++i) a[i] = *(const bf16x8*)(Ap + aB0 + (4 + i) * 1024);
    asm volatile("s_barrier" ::: "memory");
    __builtin_amdgcn_s_setprio(1);
#pragma unroll
    for (int i = 0; i < 4; ++i)
#pragma unroll
      for (int j = 0; j < 4; ++j)
        acc[4 + i][j] = __builtin_amdgcn_mfma_f32_16x16x32_bf16(a[i], b[j], acc[4 + i][j], 0, 0, 0);
    __builtin_amdgcn_s_setprio(0);
    asm volatile("s_barrier" ::: "memory");
    // ---- P3: i0-3, k-slice 1 ----
#pragma unroll
    for (int i = 0; i < 4; ++i) a[i] = *(const bf16x8*)(Ap + (aB0 ^ 32) + i * 1024);
#pragma unroll
    for (int j = 0; j < 4; ++j) b[j] = *(const bf16x8*)(Bp + (bB0 ^ 32) + j * 1024);
    asm volatile("s_barrier" ::: "memory");
    __builtin_amdgcn_s_setprio(1);
#pragma unroll
    for (int i = 0; i < 4; ++i)
#pragma unroll
      for (int j = 0; j < 4; ++j)
        acc[i][j] = __builtin_amdgcn_mfma_f32_16x16x32_bf16(a[i], b[j], acc[i][j], 0, 0, 0);
    __builtin_amdgcn_s_setprio(0);
    asm volatile("s_barrier" ::: "memory");
    // ---- P4: i4-7, k-slice 1 ; stage t+2 into slot s after reads retire ----
#pragma unroll
    for (int i = 0; i < 4; ++i) a[i] = *(const bf16x8*)(Ap + ((aB0 ^ 32) + (4 + i) * 1024));
    asm volatile("s_waitcnt lgkmcnt(0)" ::: "memory");  // all my slot-s reads retired
    asm volatile("s_barrier" ::: "memory");             // ... for ALL waves
    if (t + 2 < NT) { G2_SA(t + 2, s); G2_SB(t + 2, s); }
    __builtin_amdgcn_s_setprio(1);
#pragma unroll
    for (int i = 0; i < 4; ++i)
#pragma unroll
      for (int j = 0; j < 4; ++j)
        acc[4 + i][j] = __builtin_amdgcn_mfma_f32_16x16x32_bf16(a[i], b[j], acc[4 + i][j], 0, 0, 0);
    __builtin_amdgcn_s_setprio(0);
    asm volatile("s_barrier" ::: "memory");
  }
#undef G2_SA
#undef G2_SB

  if (SPLITS > 1) {
    bf16* dst = (bf16*)outp + (size_t)ks * M_TOK * D_DIM;
#pragma unroll
    for (int j = 0; j < 4; ++j) {
      const int col = n0 + wn * 64 + j * 16 + lr;
#pragma unroll
      for (int i = 0; i < 8; ++i) {
        const int r0 = m0 + wm * 128 + i * 16 + kg * 4;
#pragma unroll
        for (int rr = 0; rr < 4; ++rr) {
          const int row = r0 + rr;
          if (row < M_TOK) dst[(size_t)row * D_DIM + col] = (bf16)acc[i][j][rr];
        }
      }
    }
  } else {
    float* dst = (float*)outp;
#pragma unroll
    for (int j = 0; j < 4; ++j) {
      const int col = n0 + wn * 64 + j * 16 + lr;
      const float bv = bias[col];
#pragma unroll
      for (int i = 0; i < 8; ++i) {
        const int r0 = m0 + wm * 128 + i * 16 + kg * 4;
#pragma unroll
        for (int rr = 0; rr < 4; ++rr) {
          const int row = r0 + rr;
          if (row < M_TOK) dst[(size_t)row * D_DIM + col] = acc[i][j][rr] + bv;
        }
      }
    }
  }
}

// out = sum_s bf16 partial[s] + bias  (4 elems/thread)
template <int SPLITS>
__global__ __launch_bounds__(256) void k_reduce(const bf16* __restrict__ padd,
                                                const float* __restrict__ bias,
                                                float* __restrict__ out) {
  int idx = (blockIdx.x * 256 + threadIdx.x) * 4;
  if (idx >= M_TOK * D_DIM) return;
  float4 s = *(const float4*)(bias + (idx % D_DIM));
#pragma unroll
  for (int p = 0; p < SPLITS; ++p) {
    union { uint2 u; bf16 h[4]; } v;
    v.u = *(const uint2*)(padd + (size_t)p * M_TOK * D_DIM + idx);
    s.x += (float)v.h[0]; s.y += (float)v.h[1];
    s.z += (float)v.h[2]; s.w += (float)v.h[3];
  }
  *(float4*)(out + idx) = s;
}

// ---------------- launch ----------------

extern "C" void kernel_launch(void* const* d_in, const int* in_sizes, int n_in,
                              void* d_out, int out_size, void* d_ws, size_t ws_size,
                              hipStream_t stream) {
  const float* x     = (const float*)d_in[0];
  const float* W_org = (const float*)d_in[1];
  const float* b_org = (const float*)d_in[2];
  const float* w1    = (const float*)d_in[3];
  const float* b1    = (const float*)d_in[4];
  const float* mid_w = (const float*)d_in[5];
  const float* mid_b = (const float*)d_in[6];
  const float* w_out = (const float*)d_in[7];
  const float* b_out = (const float*)d_in[8];
  float* out = (float*)d_out;

  // workspace carve-up
  bf16* Xb   = (bf16*)d_ws;                         // 5120*768
  bf16* W1t  = Xb  + (size_t)M_PAD * D_DIM;         // 4096*768
  bf16* W2t  = W1t + (size_t)NR * D_DIM;            // 768*4864
  bf16* H2   = W2t + (size_t)D_DIM * K_CAT;         // 5120*4096
  float* bias    = (float*)(H2 + (size_t)M_PAD * NR);
  float* partial = bias + 1024;                     // 32*768 floats
  bf16* padd     = (bf16*)(partial + 32 * D_DIM);   // SPLITS * 4928*768 bf16

  const size_t base_bytes = (size_t)((char*)padd - (char*)d_ws);
  const size_t per_split  = (size_t)M_TOK * D_DIM * sizeof(bf16);
  int S = 1;
  if (ws_size >= base_bytes + 4 * per_split)      S = 4;
  else if (ws_size >= base_bytes + 2 * per_split) S = 2;

  k_prep_x     <<<(M_PAD * D_DIM / 4) / 256, 256, 0, stream>>>(x, Xb);
  k_prep_w1t   <<<(NR * D_DIM / 4) / 256, 256, 0, stream>>>(w1, W1t);
  k_prep_w2t_t <<<64 * 12, 256, 0, stream>>>(w_out, W2t);
  k_prep_w2t_org<<<(D_DIM * D_DIM / 4 + 255) / 256, 256, 0, stream>>>(W_org, W2t);
  k_bias_partial<<<32, 256, 0, stream>>>(b_out, partial);
  k_bias_final  <<<3, 256, 0, stream>>>(partial, b_org, bias);

  k_gemm1<<<40 * 32, 256, 0, stream>>>(Xb, W1t, H2, b1, mid_w, mid_b);

  const int red_grid = (M_TOK * D_DIM / 4 + 255) / 256;
  if (S == 4) {
    k_gemm2<4><<<20 * 3 * 4, 512, 0, stream>>>(H2, Xb, W2t, padd, bias);
    k_reduce<4><<<red_grid, 256, 0, stream>>>(padd, bias, out);
  } else if (S == 2) {
    k_gemm2<2><<<20 * 3 * 2, 512, 0, stream>>>(H2, Xb, W2t, padd, bias);
    k_reduce<2><<<red_grid, 256, 0, stream>>>(padd, bias, out);
  } else {
    k_gemm2<1><<<20 * 3, 512, 0, stream>>>(H2, Xb, W2t, out, bias);
  }
}

// Round 10
// 135.645 us; speedup vs baseline: 1.0140x; 1.0140x over previous
//
#include <hip/hip_runtime.h>
#include <hip/hip_bf16.h>

// Problem constants
#define M_TOK 4928   // B*T = 64*77
#define M_PAD 5120   // Xb/H2 row allocation (gemm2 reads 20x256 M-tiles)
#define D_DIM 768
#define NR    4096   // N*R = 1024*4
#define K_CAT 4864   // NR + D_DIM (concat-K for gemm2)
#define KT_ALL 152   // K_CAT / 32 (BK32 units)

typedef __bf16 bf16;
typedef __attribute__((ext_vector_type(8))) __bf16 bf16x8;
typedef __attribute__((ext_vector_type(4))) float f32x4;
typedef __attribute__((address_space(1))) uint32_t gu32;
typedef __attribute__((address_space(3))) uint32_t su32;

// sigma-GELU: x * sigmoid(1.702 x) = x * rcp(1 + exp2(-2.4554677 x)).
// Max abs err vs exact gelu ~1e-2 on h1; propagated through mid_w (~0.02) the
// up-path contribution is <1e-3 -- output error stays dominated by the bf16
// org-path rounding (1.56e-2 vs 5.8e-2 threshold). 5 insts (2 trans).
__device__ __forceinline__ float act_fast(float v) {
  float e = __builtin_amdgcn_exp2f(v * -2.4554677f);
  return v * __builtin_amdgcn_rcpf(1.0f + e);
}

// m204 bijective XCD swizzle: consecutive logical wgids land on one XCD.
__device__ __forceinline__ int xcd_swizzle(int orig, int nwg) {
  const int q = nwg >> 3, r = nwg & 7;
  const int x = orig & 7, rest = orig >> 3;
  return (x < r ? x * (q + 1) : r * (q + 1) + (x - r) * q) + rest;
}

// ---------------- prep kernels ----------------

__global__ __launch_bounds__(256) void k_prep_x(const float* __restrict__ x,
                                                bf16* __restrict__ Xb) {
  int idx = (blockIdx.x * 256 + threadIdx.x) * 4;
  if (idx >= M_PAD * D_DIM) return;
  int m = idx / D_DIM;
  union { uint2 u; bf16 h[4]; } o;
  if (m < M_TOK) {
    float4 v = *(const float4*)(x + idx);
    o.h[0] = (bf16)v.x; o.h[1] = (bf16)v.y; o.h[2] = (bf16)v.z; o.h[3] = (bf16)v.w;
  } else {
    o.h[0] = o.h[1] = o.h[2] = o.h[3] = (bf16)0.0f;
  }
  *(uint2*)(Xb + idx) = o.u;
}

// w1 fp32 [N=1024][D=768][R=4] -> W1t bf16 [4096 j][768 d].  One float4 of w1
// is all 4 r's of one d.  Thread = (n, d-octet): 8 contiguous float4 reads
// (128 B/lane), 4 x 16B row stores.  Grid 384.
__global__ __launch_bounds__(256) void k_prep_w1t(const float* __restrict__ w1,
                                                  bf16* __restrict__ W1t) {
  int gid = blockIdx.x * 256 + threadIdx.x;   // 1024*96 = 98304
  int n = gid / 96, oct = gid % 96;
  const float4* src = (const float4*)w1 + (size_t)n * D_DIM + oct * 8;
  bf16x8 rows[4];
#pragma unroll
  for (int d = 0; d < 8; ++d) {
    float4 v = src[d];
    rows[0][d] = (bf16)v.x; rows[1][d] = (bf16)v.y;
    rows[2][d] = (bf16)v.z; rows[3][d] = (bf16)v.w;
  }
  size_t base = (size_t)n * 4 * D_DIM + oct * 8;
#pragma unroll
  for (int r = 0; r < 4; ++r)
    *(bf16x8*)(W1t + base + (size_t)r * D_DIM) = rows[r];
}

// w_out fp32 [4096 k][768 d] -> W2t[d][k] (x0.25) via LDS 64x64 transpose.
__global__ __launch_bounds__(256) void k_prep_w2t_t(const float* __restrict__ w_out,
                                                    bf16* __restrict__ W2t) {
  __shared__ float S[64 * 65];
  const int bk = blockIdx.x & 63, bd = blockIdx.x >> 6;  // 64 k-tiles x 12 d-tiles
  const int k0 = bk * 64, d0 = bd * 64;
  const int tr = threadIdx.x >> 4;        // 0..15
  const int tc = (threadIdx.x & 15) * 4;  // 0..60
#pragma unroll
  for (int p = 0; p < 4; ++p) {
    const int kr = tr + p * 16;
    float4 v = *(const float4*)(w_out + (size_t)(k0 + kr) * D_DIM + d0 + tc);
    S[kr * 65 + tc + 0] = v.x; S[kr * 65 + tc + 1] = v.y;
    S[kr * 65 + tc + 2] = v.z; S[kr * 65 + tc + 3] = v.w;
  }
  __syncthreads();
#pragma unroll
  for (int p = 0; p < 4; ++p) {
    const int dr = tr + p * 16;
    union { uint2 u; bf16 h[4]; } o;
#pragma unroll
    for (int i = 0; i < 4; ++i) o.h[i] = (bf16)(0.25f * S[(tc + i) * 65 + dr]);
    *(uint2*)(W2t + (size_t)(d0 + dr) * K_CAT + k0 + tc) = o.u;
  }
}

// W_org fp32 [768 d][768 k] -> W2t[d][4096 + k]  (row-major: plain copy)
__global__ __launch_bounds__(256) void k_prep_w2t_org(const float* __restrict__ W_org,
                                                      bf16* __restrict__ W2t) {
  int idx = (blockIdx.x * 256 + threadIdx.x) * 4;
  if (idx >= D_DIM * D_DIM) return;
  int d = idx / D_DIM, c = idx % D_DIM;
  float4 v = *(const float4*)(W_org + idx);
  union { uint2 u; bf16 h[4]; } o;
  o.h[0] = (bf16)v.x; o.h[1] = (bf16)v.y; o.h[2] = (bf16)v.z; o.h[3] = (bf16)v.w;
  *(uint2*)(W2t + (size_t)d * K_CAT + NR + c) = o.u;
}

// bias_total[d] = b_org[d] + 0.25 * sum_n b_out[n][d]  (deterministic 2-stage)
__global__ __launch_bounds__(256) void k_bias_partial(const float* __restrict__ b_out,
                                                      float* __restrict__ partial) {
  int b = blockIdx.x;
  for (int d = threadIdx.x; d < D_DIM; d += 256) {
    float s = 0.0f;
    for (int n = b * 32; n < b * 32 + 32; ++n) s += b_out[n * D_DIM + d];
    partial[b * D_DIM + d] = s;
  }
}

// blocks 0-2: bias_total; blocks 3-18: diag[j] = mid_w[n][r][r] (j = n*4+r)
__global__ __launch_bounds__(256) void k_bias_final2(const float* __restrict__ partial,
                                                     const float* __restrict__ b_org,
                                                     const float* __restrict__ mid_w,
                                                     float* __restrict__ bias_total,
                                                     float* __restrict__ diag) {
  int b = blockIdx.x;
  if (b < 3) {
    int d = b * 256 + threadIdx.x;
    if (d >= D_DIM) return;
    float s = 0.0f;
#pragma unroll
    for (int p = 0; p < 32; ++p) s += partial[p * D_DIM + d];
    bias_total[d] = b_org[d] + 0.25f * s;
  } else {
    int j = (b - 3) * 256 + threadIdx.x;  // < 4096
    diag[j] = mid_w[(j >> 2) * 16 + (j & 3) * 5];
  }
}

// ---------------- staging helpers ----------------
// Bank-conflict swizzle (R4-verified: conflicts -> 0): 16B slot p of row r
// holds logical slot p ^ ((r>>1)&3); source pre-swizzled, ds_read XORs back.

__device__ __forceinline__ int swz_slot(int kg, int lr) {
  return (kg ^ ((lr >> 1) & 3)) << 3;  // bf16 elements
}

// 4-wave (256-thread) stage of a 128x32 bf16 tile: 2 insts/wave.
__device__ __forceinline__ void stage_tile4(const bf16* g, int ld, int row0, int col0,
                                            bf16* lds) {
  const int lane = threadIdx.x & 63;
  const int wave = threadIdx.x >> 6;  // 0..3
  const int src_slot = (lane & 3) ^ ((lane >> 3) & 3);
#pragma unroll
  for (int c = 0; c < 2; ++c) {
    const int chunk = wave * 2 + c;   // 0..7
    const int row = row0 + chunk * 16 + (lane >> 2);
    const bf16* gp = g + (size_t)row * ld + col0 + (src_slot << 3);
    __builtin_amdgcn_global_load_lds((gu32*)gp, (su32*)(lds + chunk * 512), 16, 0, 0);
  }
}

// 8-wave (512-thread) stage of a 256x32 bf16 tile: 2 insts/wave.
__device__ __forceinline__ void stage_unit8(const bf16* g, int ld, int row0, int col0,
                                            bf16* lds) {
  const int lane = threadIdx.x & 63;
  const int wave = threadIdx.x >> 6;  // 0..7
  const int src_slot = (lane & 3) ^ ((lane >> 3) & 3);
#pragma unroll
  for (int c = 0; c < 2; ++c) {
    const int chunk = wave * 2 + c;   // 0..15
    const int row = row0 + chunk * 16 + (lane >> 2);
    const bf16* gp = g + (size_t)row * ld + col0 + (src_slot << 3);
    __builtin_amdgcn_global_load_lds((gu32*)gp, (su32*)(lds + chunk * 512), 16, 0, 0);
  }
}

#define TILE_E (128 * 32)

// ---------------- GEMM1: 128x128, 4 waves, 3-slot counted-vmcnt ----------
// SWAPPED MFMA (mfma(Wfrag, Xfrag)): D[row]=H2-col, D[col]=H2-row -> each
// lane owns 4 CONSECUTIVE H2 columns at one row => 8B packed stores and
// float4 col-param loads in the epilogue.
#define PIPE_LOOP(KT0, KT1, STAGE_PAIR, BODY)                                   \
  {                                                                             \
    STAGE_PAIR(KT0, 0);                                                         \
    STAGE_PAIR((KT0) + 1, 1);                                                   \
    int ra = 0;                                                                 \
    for (int kt = (KT0); kt < (KT1); ++kt) {                                    \
      if (kt + 1 < (KT1)) { asm volatile("s_waitcnt vmcnt(4)" ::: "memory"); }  \
      else                { asm volatile("s_waitcnt vmcnt(0)" ::: "memory"); }  \
      asm volatile("s_barrier" ::: "memory");                                   \
      const int rs = ra + 2 >= 3 ? ra - 1 : ra + 2;                             \
      BODY(ra);                                                                 \
      if (kt + 2 < (KT1)) STAGE_PAIR(kt + 2, rs);                               \
      ra = (ra + 1 == 3) ? 0 : ra + 1;                                          \
    }                                                                           \
  }

// GEMM1: Xb x W1t -> H2 bf16 [4992 rows written, 5120 alloc]
// (rows >= 4992 of H2 stay stale workspace: finite values, only feed
//  discarded output rows -- output remains deterministic)
__global__ __launch_bounds__(256) void k_gemm1(const bf16* __restrict__ Xb,
                                               const bf16* __restrict__ W1t,
                                               bf16* __restrict__ H2,
                                               const float* __restrict__ b1,
                                               const float* __restrict__ diag,
                                               const float* __restrict__ midb) {
  __shared__ bf16 As[3][TILE_E];
  __shared__ bf16 Bs[3][TILE_E];
  const int wgid = xcd_swizzle(blockIdx.x, 39 * 32);
  const int bmt = wgid >> 5;             // 39 M-tiles of 128
  const int bnt = wgid & 31;             // 32 N-tiles (consecutive share A-panel)
  const int m0 = bmt * 128, n0 = bnt * 128;
  const int lane = threadIdx.x & 63;
  const int wave = threadIdx.x >> 6;
  const int wm = wave >> 1, wn = wave & 1;
  const int lr = lane & 15, kg = lane >> 4;
  const int slot = swz_slot(kg, lr);

  f32x4 acc[4][4];
#pragma unroll
  for (int i = 0; i < 4; ++i)
#pragma unroll
    for (int j = 0; j < 4; ++j) acc[i][j] = (f32x4)(0.0f);

#define G1_STAGE(kt, buf)                                   \
  {                                                         \
    stage_tile4(Xb, D_DIM, m0, (kt) * 32, As[(buf)]);       \
    stage_tile4(W1t, D_DIM, n0, (kt) * 32, Bs[(buf)]);      \
  }
#define G1_BODY(cur)                                                         \
  {                                                                          \
    bf16x8 a[4], b[4];                                                       \
    _Pragma("unroll") for (int i = 0; i < 4; ++i)                            \
      a[i] = *(const bf16x8*)(As[(cur)] + (wm * 64 + i * 16 + lr) * 32 + slot); \
    _Pragma("unroll") for (int j = 0; j < 4; ++j)                            \
      b[j] = *(const bf16x8*)(Bs[(cur)] + (wn * 64 + j * 16 + lr) * 32 + slot); \
    _Pragma("unroll") for (int i = 0; i < 4; ++i)                            \
      _Pragma("unroll") for (int j = 0; j < 4; ++j)                          \
        acc[i][j] = __builtin_amdgcn_mfma_f32_16x16x32_bf16(b[j], a[i], acc[i][j], 0, 0, 0); \
  }

  PIPE_LOOP(0, 24, G1_STAGE, G1_BODY)
#undef G1_STAGE
#undef G1_BODY

  // epilogue: lane owns H2[mr][jcb..jcb+3] per frag
#pragma unroll
  for (int j = 0; j < 4; ++j) {
    const int jcb = n0 + wn * 64 + j * 16 + kg * 4;
    const float4 b1v = *(const float4*)(b1 + jcb);
    const float4 dgv = *(const float4*)(diag + jcb);
    const float4 mbv = *(const float4*)(midb + jcb);
#pragma unroll
    for (int i = 0; i < 4; ++i) {
      const int mr = m0 + wm * 64 + i * 16 + lr;
      union { uint2 u; bf16 h[4]; } o;
      float h;
      h = act_fast(acc[i][j][0] + b1v.x); o.h[0] = (bf16)act_fast(h * dgv.x + mbv.x);
      h = act_fast(acc[i][j][1] + b1v.y); o.h[1] = (bf16)act_fast(h * dgv.y + mbv.y);
      h = act_fast(acc[i][j][2] + b1v.z); o.h[2] = (bf16)act_fast(h * dgv.z + mbv.z);
      h = act_fast(acc[i][j][3] + b1v.w); o.h[3] = (bf16)act_fast(h * dgv.w + mbv.w);
      *(uint2*)(H2 + (size_t)mr * NR + jcb) = o.u;
    }
  }
}

// ---------------- GEMM2: 256x256 8-wave engine (R8 schedule) ----------------
// Per K-tile (BK=32): 2 phases of {ds_read subtile || stage -> barrier ->
// setprio(1) 16 MFMA setprio(0) -> barrier}; counted vmcnt(8), 3 tiles in
// flight; swapped MFMA for the vectorized epilogue.

#define ENGINE(KT0, KT1, STAGE_A, STAGE_B)                                      \
  {                                                                             \
    STAGE_A((KT0) + 0, 0); STAGE_B((KT0) + 0, 0);                               \
    STAGE_A((KT0) + 1, 1); STAGE_B((KT0) + 1, 1);                               \
    STAGE_A((KT0) + 2, 2); STAGE_B((KT0) + 2, 2);                               \
    asm volatile("s_waitcnt vmcnt(8)" ::: "memory");                            \
    asm volatile("s_barrier" ::: "memory");                                     \
    for (int t = (KT0); t < (KT1); ++t) {                                       \
      const int s  = (t - (KT0)) & 3;                                           \
      const int st = (t - (KT0) + 3) & 3;                                       \
      const bool more = (t + 3 < (KT1));                                        \
      bf16x8 a[8], b[4];                                                        \
      _Pragma("unroll") for (int i = 0; i < 4; ++i)                             \
        a[i] = *(const bf16x8*)(As[s] + aBase + i * 512);                       \
      _Pragma("unroll") for (int j = 0; j < 4; ++j)                             \
        b[j] = *(const bf16x8*)(Bs[s] + bBase + j * 512);                       \
      if (more) { STAGE_A(t + 3, st); }                                         \
      asm volatile("s_barrier" ::: "memory");                                   \
      __builtin_amdgcn_s_setprio(1);                                            \
      _Pragma("unroll") for (int i = 0; i < 4; ++i)                             \
        _Pragma("unroll") for (int j = 0; j < 4; ++j)                           \
          acc[i][j] = __builtin_amdgcn_mfma_f32_16x16x32_bf16(b[j], a[i], acc[i][j], 0, 0, 0); \
      __builtin_amdgcn_s_setprio(0);                                            \
      asm volatile("s_barrier" ::: "memory");                                   \
      _Pragma("unroll") for (int i = 0; i < 4; ++i)                             \
        a[4 + i] = *(const bf16x8*)(As[s] + aBase + 2048 + i * 512);            \
      if (more) { STAGE_B(t + 3, st); }                                         \
      {                                                                         \
        int ahead = ((KT1) - 1) - (t + 1);                                      \
        if (ahead >= 2)      { asm volatile("s_waitcnt vmcnt(8)" ::: "memory"); } \
        else if (ahead == 1) { asm volatile("s_waitcnt vmcnt(4)" ::: "memory"); } \
        else                 { asm volatile("s_waitcnt vmcnt(0)" ::: "memory"); } \
      }                                                                         \
      asm volatile("s_barrier" ::: "memory");                                   \
      __builtin_amdgcn_s_setprio(1);                                            \
      _Pragma("unroll") for (int i = 0; i < 4; ++i)                             \
        _Pragma("unroll") for (int j = 0; j < 4; ++j)                           \
          acc[4 + i][j] = __builtin_amdgcn_mfma_f32_16x16x32_bf16(b[j], a[4 + i], acc[4 + i][j], 0, 0, 0); \
      __builtin_amdgcn_s_setprio(0);                                            \
      asm volatile("s_barrier" ::: "memory");                                   \
    }                                                                           \
  }

// GEMM2: A = [H2 | Xb] (K=4864) x W2t[768,4864] -> bf16 partials / fp32 out.
template <int SPLITS>
__global__ __launch_bounds__(512) void k_gemm2(const bf16* __restrict__ H2,
                                               const bf16* __restrict__ Xb,
                                               const bf16* __restrict__ W2t,
                                               void* __restrict__ outp,
                                               const float* __restrict__ bias) {
  __shared__ bf16 As[4][8192];
  __shared__ bf16 Bs[4][8192];
  const int nwg = 20 * 3 * SPLITS;
  const int wgid = xcd_swizzle(blockIdx.x, nwg);
  const int bmt = wgid / (3 * SPLITS);
  const int rem = wgid % (3 * SPLITS);
  const int ks  = rem / 3;
  const int bnt = rem % 3;               // 3 consecutive share A-panel
  const int m0 = bmt * 256, n0 = bnt * 256;
  const int lane = threadIdx.x & 63;
  const int wave = threadIdx.x >> 6;
  const int wm = wave >> 2, wn = wave & 3;
  const int lr = lane & 15, kg = lane >> 4;
  const int slotE = swz_slot(kg, lr);
  const int aBase = (wm * 128 + lr) * 32 + slotE;
  const int bBase = (wn * 64 + lr) * 32 + slotE;
  constexpr int KT_PER = KT_ALL / SPLITS;
  const int kt0 = ks * KT_PER, kt1 = kt0 + KT_PER;

  f32x4 acc[8][4];
#pragma unroll
  for (int i = 0; i < 8; ++i)
#pragma unroll
    for (int j = 0; j < 4; ++j) acc[i][j] = (f32x4)(0.0f);

#define G2_SA(kt, buf)                                                  \
  {                                                                     \
    const int k0s = (kt) * 32;                                          \
    if (k0s < NR) stage_unit8(H2, NR, m0, k0s, As[(buf)]);              \
    else          stage_unit8(Xb, D_DIM, m0, k0s - NR, As[(buf)]);      \
  }
#define G2_SB(kt, buf) stage_unit8(W2t, K_CAT, n0, (kt) * 32, Bs[(buf)])
  ENGINE(kt0, kt1, G2_SA, G2_SB)
#undef G2_SA
#undef G2_SB

  // epilogue: lane owns dst[mr][cb..cb+3] per frag (swapped-MFMA layout)
  if (SPLITS > 1) {
    bf16* dst = (bf16*)outp + (size_t)ks * M_TOK * D_DIM;
#pragma unroll
    for (int j = 0; j < 4; ++j) {
      const int cb = n0 + wn * 64 + j * 16 + kg * 4;
#pragma unroll
      for (int i = 0; i < 8; ++i) {
        const int mr = m0 + wm * 128 + i * 16 + lr;
        if (mr < M_TOK) {
          union { uint2 u; bf16 h[4]; } o;
          o.h[0] = (bf16)acc[i][j][0]; o.h[1] = (bf16)acc[i][j][1];
          o.h[2] = (bf16)acc[i][j][2]; o.h[3] = (bf16)acc[i][j][3];
          *(uint2*)(dst + (size_t)mr * D_DIM + cb) = o.u;
        }
      }
    }
  } else {
    float* dst = (float*)outp;
#pragma unroll
    for (int j = 0; j < 4; ++j) {
      const int cb = n0 + wn * 64 + j * 16 + kg * 4;
      const f32x4 bv = *(const f32x4*)(bias + cb);
#pragma unroll
      for (int i = 0; i < 8; ++i) {
        const int mr = m0 + wm * 128 + i * 16 + lr;
        if (mr < M_TOK) {
          f32x4 o = acc[i][j] + bv;
          *(f32x4*)(dst + (size_t)mr * D_DIM + cb) = o;
        }
      }
    }
  }
}

// out = sum_s bf16 partial[s] + bias  (4 elems/thread)
template <int SPLITS>
__global__ __launch_bounds__(256) void k_reduce(const bf16* __restrict__ padd,
                                                const float* __restrict__ bias,
                                                float* __restrict__ out) {
  int idx = (blockIdx.x * 256 + threadIdx.x) * 4;
  if (idx >= M_TOK * D_DIM) return;
  float4 s = *(const float4*)(bias + (idx % D_DIM));
#pragma unroll
  for (int p = 0; p < SPLITS; ++p) {
    union { uint2 u; bf16 h[4]; } v;
    v.u = *(const uint2*)(padd + (size_t)p * M_TOK * D_DIM + idx);
    s.x += (float)v.h[0]; s.y += (float)v.h[1];
    s.z += (float)v.h[2]; s.w += (float)v.h[3];
  }
  *(float4*)(out + idx) = s;
}

// ---------------- launch ----------------

extern "C" void kernel_launch(void* const* d_in, const int* in_sizes, int n_in,
                              void* d_out, int out_size, void* d_ws, size_t ws_size,
                              hipStream_t stream) {
  const float* x     = (const float*)d_in[0];
  const float* W_org = (const float*)d_in[1];
  const float* b_org = (const float*)d_in[2];
  const float* w1    = (const float*)d_in[3];
  const float* b1    = (const float*)d_in[4];
  const float* mid_w = (const float*)d_in[5];
  const float* mid_b = (const float*)d_in[6];
  const float* w_out = (const float*)d_in[7];
  const float* b_out = (const float*)d_in[8];
  float* out = (float*)d_out;

  // workspace carve-up
  bf16* Xb   = (bf16*)d_ws;                         // 5120*768
  bf16* W1t  = Xb  + (size_t)M_PAD * D_DIM;         // 4096*768
  bf16* W2t  = W1t + (size_t)NR * D_DIM;            // 768*4864
  bf16* H2   = W2t + (size_t)D_DIM * K_CAT;         // 5120*4096
  float* bias    = (float*)(H2 + (size_t)M_PAD * NR);
  float* partial = bias + 1024;                     // 32*768 floats
  float* diag    = partial + 32 * D_DIM;            // 4096 floats
  bf16* padd     = (bf16*)(diag + NR);              // SPLITS * 4928*768 bf16

  const size_t base_bytes = (size_t)((char*)padd - (char*)d_ws);
  const size_t per_split  = (size_t)M_TOK * D_DIM * sizeof(bf16);
  int S = 1;
  if (ws_size >= base_bytes + 4 * per_split)      S = 4;
  else if (ws_size >= base_bytes + 2 * per_split) S = 2;

  k_prep_x     <<<(M_PAD * D_DIM / 4) / 256, 256, 0, stream>>>(x, Xb);
  k_prep_w1t   <<<384, 256, 0, stream>>>(w1, W1t);
  k_prep_w2t_t <<<64 * 12, 256, 0, stream>>>(w_out, W2t);
  k_prep_w2t_org<<<(D_DIM * D_DIM / 4 + 255) / 256, 256, 0, stream>>>(W_org, W2t);
  k_bias_partial<<<32, 256, 0, stream>>>(b_out, partial);
  k_bias_final2 <<<19, 256, 0, stream>>>(partial, b_org, mid_w, bias, diag);

  k_gemm1<<<39 * 32, 256, 0, stream>>>(Xb, W1t, H2, b1, diag, mid_b);

  const int red_grid = (M_TOK * D_DIM / 4 + 255) / 256;
  if (S == 4) {
    k_gemm2<4><<<20 * 3 * 4, 512, 0, stream>>>(H2, Xb, W2t, padd, bias);
    k_reduce<4><<<red_grid, 256, 0, stream>>>(padd, bias, out);
  } else if (S == 2) {
    k_gemm2<2><<<20 * 3 * 2, 512, 0, stream>>>(H2, Xb, W2t, padd, bias);
    k_reduce<2><<<red_grid, 256, 0, stream>>>(padd, bias, out);
  } else {
    k_gemm2<1><<<20 * 3, 512, 0, stream>>>(H2, Xb, W2t, out, bias);
  }
}